// Round 18
// baseline (54.778 us; speedup 1.0000x reference)
//
#include <hip/hip_runtime.h>
#include <hip/hip_bf16.h>
#include <stdint.h>

// Shapes: B=8, T=2048, E=1024, H=64
// wei[t][s] = k[t]·q[s] * 0.125 (k plays "query"), causal s<=t.
// 0.125*log2(e) folded into Wk so softmax uses exp2 directly.

typedef __attribute__((ext_vector_type(4))) float f32x4;
typedef __attribute__((ext_vector_type(4))) short s16x4;
typedef __attribute__((ext_vector_type(8))) short s16x8;
typedef __attribute__((ext_vector_type(2))) unsigned int u32x2;
typedef __attribute__((ext_vector_type(4))) unsigned int u32x4;

__device__ __forceinline__ unsigned bf16pack(float a, float b){
    unsigned ua = __builtin_bit_cast(unsigned, a);
    unsigned ub = __builtin_bit_cast(unsigned, b);
    return ((ua + 0x8000u) >> 16) | ((ub + 0x8000u) & 0xffff0000u);
}
__device__ __forceinline__ unsigned short bf16one(float a){
    return (unsigned short)((__builtin_bit_cast(unsigned, a) + 0x8000u) >> 16);
}
// async global->LDS DMA, 16B per lane; LDS dest = uniform base + lane*16 (linear)
__device__ __forceinline__ void gload16(const void* g, unsigned short* l){
    __builtin_amdgcn_global_load_lds((const __attribute__((address_space(1))) unsigned int*)g,
                                     (__attribute__((address_space(3))) unsigned int*)l, 16, 0, 0);
}

// ---------------- W prep v2 (passed r17): coalesced 64x64-tile transpose, 48 blocks ----------------
__global__ __launch_bounds__(256) void wprep_kernel(const float* __restrict__ Wk,
                                                    const float* __restrict__ Wq,
                                                    const float* __restrict__ Wv,
                                                    unsigned short* __restrict__ WT){
    __shared__ unsigned short lt[64][66];  // padded: column reads spread across banks
    int w = blockIdx.y;            // matrix 0..2
    int tr = blockIdx.x;           // k-tile 0..15
    const float* src = (w == 0) ? Wk : (w == 1) ? Wq : Wv;
    float scale = (w == 0) ? 0.18033688011112042f : 1.0f;  // 0.125 * log2(e)
    int tid = threadIdx.x;
    int row = tid >> 2, seg = tid & 3;
    const float* g = src + (size_t)(tr * 64 + row) * 64 + seg * 16;
    unsigned short* ld = &lt[row][seg * 16];
    #pragma unroll
    for (int c = 0; c < 4; c++){
        f32x4 v = *(const f32x4*)(g + c * 4);
        u32x2 pk;
        pk[0] = bf16pack(v[0] * scale, v[1] * scale);
        pk[1] = bf16pack(v[2] * scale, v[3] * scale);
        *(u32x2*)(ld + c * 4) = pk;
    }
    __syncthreads();
    int n = tid >> 2, ks = tid & 3;
    s16x8 o0, o1;
    #pragma unroll
    for (int e = 0; e < 8; e++){
        o0[e] = (short)lt[ks * 16 + e][n];
        o1[e] = (short)lt[ks * 16 + 8 + e][n];
    }
    unsigned short* dst = WT + (size_t)(w * 64 + n) * 1024 + tr * 64 + ks * 16;
    *(s16x8*)(dst)     = o0;
    *(s16x8*)(dst + 8) = o1;
}

// ---------------- Projections v10 (passed r9-r17): full DMA staging, 512x256 ----------------
__global__ __launch_bounds__(256) void proj_kernel(const float* __restrict__ x,
                                                   const unsigned short* __restrict__ WT,
                                                   unsigned short* __restrict__ kb,
                                                   unsigned short* __restrict__ qb,
                                                   unsigned short* __restrict__ vT){
    __shared__ unsigned short smem[32768];  // xb: 0/4096 (8KB each); wb: 8192/20480 (24KB each)
    int tid = threadIdx.x; int l = tid & 63; int w = tid >> 6;
    int lr = l & 15, lg = l >> 4;
    int row0 = blockIdx.x * 32;
    int b = row0 >> 11, t0 = row0 & 2047;
    const float* xbase = x + (size_t)row0 * 1024;

    auto stage = [&](int k0, int buf){
        #pragma unroll
        for (int t = 0; t < 2; t++){
            int i = w * 2 + t;
            int r = i * 4 + (l >> 4);
            int c = l & 15;
            gload16(xbase + (size_t)r * 1024 + k0 + ((c ^ ((r & 7) << 1)) * 4),
                    smem + buf * 4096 + i * 512);
        }
        #pragma unroll
        for (int u = 0; u < 6; u++){
            int i = w * 6 + u;
            int r = i * 8 + (l >> 3);
            int c = l & 7;
            gload16(WT + (size_t)r * 1024 + k0 + ((c ^ (r & 7)) * 8),
                    smem + 8192 + buf * 12288 + i * 512);
        }
    };

    f32x4 acc[2][3] = {};
    stage(0, 0);
    __syncthreads();
    int cur = 0;
    for (int k0 = 0; k0 < 1024; k0 += 64){
        int kn = (k0 + 64 < 1024) ? (k0 + 64) : 960;
        stage(kn, cur ^ 1);
        s16x8 af[2][2];
        #pragma unroll
        for (int mf = 0; mf < 2; mf++){
            int r = mf * 16 + lr;
            const unsigned short* xrow = smem + cur * 4096 + r * 128;
            #pragma unroll
            for (int kc = 0; kc < 2; kc++){
                int c0 = (kc * 8 + lg * 2) ^ ((r & 7) << 1);
                f32x4 v0 = *(const f32x4*)(xrow + c0 * 8);
                f32x4 v1 = *(const f32x4*)(xrow + c0 * 8 + 8);
                u32x4 pk;
                pk[0] = bf16pack(v0[0], v0[1]); pk[1] = bf16pack(v0[2], v0[3]);
                pk[2] = bf16pack(v1[0], v1[1]); pk[3] = bf16pack(v1[2], v1[3]);
                af[mf][kc] = __builtin_bit_cast(s16x8, pk);
            }
        }
        #pragma unroll
        for (int nn = 0; nn < 3; nn++){
            int r = (w * 3 + nn) * 16 + lr;
            const unsigned short* wrow = smem + 8192 + cur * 12288 + r * 64;
            s16x8 b0 = *(const s16x8*)(wrow + ((lg       ^ (r & 7)) * 8));
            s16x8 b1 = *(const s16x8*)(wrow + (((4 + lg) ^ (r & 7)) * 8));
            acc[0][nn] = __builtin_amdgcn_mfma_f32_16x16x32_bf16(af[0][0], b0, acc[0][nn], 0, 0, 0);
            acc[0][nn] = __builtin_amdgcn_mfma_f32_16x16x32_bf16(af[0][1], b1, acc[0][nn], 0, 0, 0);
            acc[1][nn] = __builtin_amdgcn_mfma_f32_16x16x32_bf16(af[1][0], b0, acc[1][nn], 0, 0, 0);
            acc[1][nn] = __builtin_amdgcn_mfma_f32_16x16x32_bf16(af[1][1], b1, acc[1][nn], 0, 0, 0);
        }
        __syncthreads();
        cur ^= 1;
    }
    #pragma unroll
    for (int mf = 0; mf < 2; mf++)
        #pragma unroll
        for (int nn = 0; nn < 3; nn++){
            int col = (w * 3 + nn) * 16 + lr;
            int row = mf * 16 + lg * 4;
            #pragma unroll
            for (int r = 0; r < 4; r++)
                smem[(row + r) * 200 + col] = bf16one(acc[mf][nn][r]);
        }
    __syncthreads();
    {
        int r2 = tid >> 3, c2 = (tid & 7) * 16;
        const unsigned short* srowp = smem + r2 * 200 + c2;
        unsigned short* dst = (c2 < 64)
            ? kb + (size_t)(b * 2048 + t0 + r2) * 64 + c2
            : qb + (size_t)(b * 2048 + t0 + r2) * 64 + (c2 - 64);
        *(s16x8*)(dst)     = *(const s16x8*)(srowp);
        *(s16x8*)(dst + 8) = *(const s16x8*)(srowp + 8);
        int h = tid >> 2, q3 = tid & 3;
        s16x8 vv;
        #pragma unroll
        for (int e = 0; e < 8; e++)
            vv[e] = smem[(q3 * 8 + e) * 200 + 128 + h];
        *(s16x8*)(vT + (size_t)(b * 64 + h) * 2048 + t0 + q3 * 8) = vv;
    }
}

// ---------------- attn phase A v12: 128-s chunks (half the iterations/barriers) ----------------
// grid 8*32*NS: b = bx&7 (XCD-pinned); r = bx>>3: bt = 31 - r/NS (heavy first), strip = r%NS.
// Chunk j covers s in [j*128, j*128+127]; nch = (bt+2)/2; only chunk jmax straddles the diag
// (128*j <= 64*bt for all j < jmax); over-reach s > t0+63 masked by the global s>t compare.
// LDS 64 KB (K[2][128][64] + V[2][64][128]) -> 2 blocks/CU.
template<int NS>
__global__ __launch_bounds__(256) void attn_part_kernel(const unsigned short* __restrict__ kb,
                                                        const unsigned short* __restrict__ qb,
                                                        const unsigned short* __restrict__ vT,
                                                        float* __restrict__ out,
                                                        float* __restrict__ accp,
                                                        float* __restrict__ ml){
    __shared__ unsigned short Klds[2][128 * 64];
    __shared__ unsigned short Vlds[2][64 * 128];
    int tid = threadIdx.x; int l = tid & 63; int w = tid >> 6;
    int lr = l & 15, lg = l >> 4;
    int bx = blockIdx.x;
    int b = bx & 7;
    int r9 = bx >> 3;
    int bt = 31 - (r9 / NS);
    int strip = r9 % NS;
    int t0 = bt * 64;
    int tw = t0 + w * 16;
    const unsigned short* fqp = kb + (size_t)(b * 2048 + tw + lr) * 64 + lg * 8;
    s16x8 fq0 = *(const s16x8*)(fqp);
    s16x8 fq1 = *(const s16x8*)(fqp + 32);
    const unsigned short* qbb = qb + (size_t)b * 2048 * 64;
    const unsigned short* vbb = vT + (size_t)b * 64 * 2048;

    int nch = (bt + 2) >> 1;
    int jmax = nch - 1;
    f32x4 acc[4] = {};
    float mrun = -3.0e38f, lrun = 0.0f;

    // stage chunk j (clamped) into buffer buf: 8 DMA instrs/wave (4 K-blocks + 4 V-blocks of 1KB)
    auto stageC = [&](int j, int buf){
        int jc = (j <= jmax) ? j : jmax;
        int s0 = jc * 128;
        #pragma unroll
        for (int t = 0; t < 4; t++){
            int i = w * 4 + t;
            int kr = i * 8 + (l >> 3);     // K row 0..127 (128B rows, 8 chunks)
            int kc = l & 7;
            gload16(qbb + (size_t)(s0 + kr) * 64 + ((kc ^ (kr & 7)) * 8), &Klds[buf][i * 512]);
        }
        #pragma unroll
        for (int t = 0; t < 4; t++){
            int i = w * 4 + t;
            int vr = i * 4 + (l >> 4);     // V row 0..63 (256B rows, 16 chunks)
            int vc = l & 15;
            gload16(vbb + (size_t)vr * 2048 + s0 + ((vc ^ ((vr & 7) << 1)) * 8), &Vlds[buf][i * 512]);
        }
    };

    stageC(strip, 0);
    __syncthreads();
    int cur = 0;
    for (int j = strip; j <= jmax; j += NS){
        stageC(j + NS, cur ^ 1);
        int s0 = j * 128;
        // S^T: C[s][t] = sum_d q[s][d]*k[t][d]; 8 s-subtiles of 16
        f32x4 Cs[8];
        #pragma unroll
        for (int n = 0; n < 8; n++){
            int r = n * 16 + lr;
            const unsigned short* ka = &Klds[cur][r * 64];
            s16x8 k0 = *(const s16x8*)(ka + ((lg       ^ (r & 7)) * 8));
            s16x8 k1 = *(const s16x8*)(ka + (((4 + lg) ^ (r & 7)) * 8));
            f32x4 z = {};
            z     = __builtin_amdgcn_mfma_f32_16x16x32_bf16(k0, fq0, z, 0, 0, 0);
            Cs[n] = __builtin_amdgcn_mfma_f32_16x16x32_bf16(k1, fq1, z, 0, 0, 0);
        }
        if (j == jmax){  // only chunk that can straddle the diagonal; global s>t mask
            int tg = tw + lr;
            #pragma unroll
            for (int n = 0; n < 8; n++){
                int sg = s0 + n * 16 + lg * 4;
                #pragma unroll
                for (int rr = 0; rr < 4; rr++)
                    if (sg + rr > tg) Cs[n][rr] = -3.0e38f;
            }
        }
        float pm = -3.0e38f;
        #pragma unroll
        for (int n = 0; n < 8; n++)
            #pragma unroll
            for (int rr = 0; rr < 4; rr++) pm = fmaxf(pm, Cs[n][rr]);
        pm = fmaxf(pm, __shfl_xor(pm, 16));
        pm = fmaxf(pm, __shfl_xor(pm, 32));
        // exact defer-rescale: skip O(acc) rescale while exp2(C-m~) <= 2^8 stays bounded
        float mnew;
        if (__all(pm <= mrun + 8.0f)){
            mnew = mrun;
        } else {
            mnew = fmaxf(mrun, pm);
            float scl = exp2f(mrun - mnew);
            lrun *= scl;
            #pragma unroll
            for (int h16 = 0; h16 < 4; h16++) acc[h16] *= scl;
        }
        // exp + pack fused per-n (p never persists); ps accumulates
        float ps = 0.0f;
        s16x4 pb[8];
        #pragma unroll
        for (int n = 0; n < 8; n++){
            float e0 = exp2f(Cs[n][0] - mnew), e1 = exp2f(Cs[n][1] - mnew);
            float e2 = exp2f(Cs[n][2] - mnew), e3 = exp2f(Cs[n][3] - mnew);
            ps += (e0 + e1) + (e2 + e3);
            u32x2 t; t[0] = bf16pack(e0, e1); t[1] = bf16pack(e2, e3);
            pb[n] = __builtin_bit_cast(s16x4, t);
        }
        ps += __shfl_xor(ps, 16);
        ps += __shfl_xor(ps, 32);
        lrun += ps;
        mrun = mnew;
        // out^T: C[h][t] += V^T[h][s] * P^T[s][t]; 8 s-slices of 16
        #pragma unroll
        for (int h16 = 0; h16 < 4; h16++){
            int r = h16 * 16 + lr;
            const unsigned short* va = &Vlds[cur][r * 128];
            #pragma unroll
            for (int sl = 0; sl < 8; sl++){
                int ch = sl * 2 + (lg >> 1);
                s16x4 fv = *(const s16x4*)(va + ((ch ^ ((r & 7) << 1)) * 8) + (lg & 1) * 4);
                acc[h16] = __builtin_amdgcn_mfma_f32_16x16x16bf16_1k(fv, pb[sl], acc[h16], 0, 0, 0);
            }
        }
        __syncthreads();
        cur ^= 1;
    }
    // write raw partial: strip0 -> out, strip s>0 -> accp[s-1]; ml per t-row
    float* accdst = (strip == 0) ? out : (accp + (size_t)(strip - 1) * (8 * 2048 * 64));
    #pragma unroll
    for (int h16 = 0; h16 < 4; h16++)
        *(f32x4*)(accdst + (size_t)(b * 2048 + tw + lr) * 64 + h16 * 16 + lg * 4) = acc[h16];
    if (lg == 0){
        int idx = ((strip * 8 + b) * 32 + bt) * 64 + w * 16 + lr;
        ml[idx * 2]     = mrun;
        ml[idx * 2 + 1] = lrun;
    }
}

// ---------------- attn phase B: merge NS strips per tile (XCD-aligned grid) ----------------
template<int NS>
__global__ __launch_bounds__(256) void attn_merge_kernel(const float* __restrict__ accp,
                                                         const float* __restrict__ ml,
                                                         float* __restrict__ out){
    int bx = blockIdx.x;
    int b = bx & 7, bt = bx >> 3;
    int tid = threadIdx.x;
    int row = tid >> 2, cg = (tid & 3) * 16;
    float m[NS], lv[NS];
    float mg = -3.0e38f;
    #pragma unroll
    for (int s = 0; s < NS; s++){
        int idx = (((s * 8 + b) * 32 + bt) * 64 + row) * 2;
        m[s] = ml[idx]; lv[s] = ml[idx + 1];
        mg = fmaxf(mg, m[s]);
    }
    float wt[NS]; float lt = 0.0f;
    #pragma unroll
    for (int s = 0; s < NS; s++){ wt[s] = exp2f(m[s] - mg); lt += lv[s] * wt[s]; }
    float inv = 1.0f / lt;
    size_t base = (size_t)(b * 2048 + bt * 64 + row) * 64 + cg;
    #pragma unroll
    for (int g = 0; g < 4; g++){
        f32x4 o = (*(const f32x4*)(out + base + g * 4)) * wt[0];
        #pragma unroll
        for (int s = 1; s < NS; s++)
            o += (*(const f32x4*)(accp + (size_t)(s - 1) * (8 * 2048 * 64) + base + g * 4)) * wt[s];
        o *= inv;
        *(f32x4*)(out + base + g * 4) = o;
    }
}

// ---------------- Flash attention v8 (fallback if ws too small; passed r8/r9) ----------------
__global__ __launch_bounds__(256) void attn_kernel(const unsigned short* __restrict__ kb,
                                                   const unsigned short* __restrict__ qb,
                                                   const unsigned short* __restrict__ vT,
                                                   float* __restrict__ out){
    __shared__ unsigned short Klds[2][64 * 64];
    __shared__ unsigned short Vlds[2][64 * 64];
    int tid = threadIdx.x; int l = tid & 63; int w = tid >> 6;
    int lr = l & 15, lg = l >> 4;
    int bx = blockIdx.x;
    int b = bx & 7;
    int bt = bx >> 3;
    int t0 = bt * 64;
    int tw = t0 + w * 16;
    const unsigned short* fqp = kb + (size_t)(b * 2048 + tw + lr) * 64 + lg * 8;
    s16x8 fq0 = *(const s16x8*)(fqp);
    s16x8 fq1 = *(const s16x8*)(fqp + 32);
    const unsigned short* qbb = qb + (size_t)b * 2048 * 64;
    const unsigned short* vbb = vT + (size_t)b * 64 * 2048;
    int srhi = l >> 3;
    int schk = l & 7;
    f32x4 acc[4] = {};
    float mrun = -3.0e38f, lrun = 0.0f;
    #pragma unroll
    for (int t = 0; t < 2; t++){
        int ti = w * 2 + t;
        int row = ti * 8 + srhi;
        gload16(qbb + (size_t)row * 64 + ((schk ^ (row & 7)) * 8), &Klds[0][ti * 512]);
        gload16(vbb + (size_t)row * 2048 + ((schk ^ (row & 7)) * 8), &Vlds[0][ti * 512]);
    }
    __syncthreads();
    int cur = 0;
    for (int c = 0; c <= bt; ++c){
        int nc = (c + 1 <= bt) ? (c + 1) : bt;
        int ns0 = nc * 64;
        #pragma unroll
        for (int t = 0; t < 2; t++){
            int ti = w * 2 + t;
            int row = ti * 8 + srhi;
            gload16(qbb + (size_t)(ns0 + row) * 64 + ((schk ^ (row & 7)) * 8), &Klds[cur ^ 1][ti * 512]);
            gload16(vbb + (size_t)row * 2048 + ns0 + ((schk ^ (row & 7)) * 8), &Vlds[cur ^ 1][ti * 512]);
        }
        f32x4 Cs[4];
        #pragma unroll
        for (int n = 0; n < 4; n++){
            int r = n * 16 + lr;
            const unsigned short* ka = &Klds[cur][r * 64];
            s16x8 k0 = *(const s16x8*)(ka + ((lg       ^ (r & 7)) * 8));
            s16x8 k1 = *(const s16x8*)(ka + (((4 + lg) ^ (r & 7)) * 8));
            f32x4 z = {};
            z     = __builtin_amdgcn_mfma_f32_16x16x32_bf16(k0, fq0, z, 0, 0, 0);
            Cs[n] = __builtin_amdgcn_mfma_f32_16x16x32_bf16(k1, fq1, z, 0, 0, 0);
        }
        if (c == bt){
            #pragma unroll
            for (int n = 0; n < 4; n++)
                #pragma unroll
                for (int r = 0; r < 4; r++)
                    if (n * 16 + lg * 4 + r > w * 16 + lr) Cs[n][r] = -3.0e38f;
        }
        float pm = -3.0e38f;
        #pragma unroll
        for (int n = 0; n < 4; n++)
            #pragma unroll
            for (int r = 0; r < 4; r++) pm = fmaxf(pm, Cs[n][r]);
        pm = fmaxf(pm, __shfl_xor(pm, 16));
        pm = fmaxf(pm, __shfl_xor(pm, 32));
        float mnew = fmaxf(mrun, pm);
        float scl = exp2f(mrun - mnew);
        float p[4][4]; float ps = 0.0f;
        #pragma unroll
        for (int n = 0; n < 4; n++)
            #pragma unroll
            for (int r = 0; r < 4; r++){ float e = exp2f(Cs[n][r] - mnew); p[n][r] = e; ps += e; }
        ps += __shfl_xor(ps, 16);
        ps += __shfl_xor(ps, 32);
        lrun = lrun * scl + ps;
        mrun = mnew;
        #pragma unroll
        for (int h16 = 0; h16 < 4; h16++) acc[h16] *= scl;
        s16x4 pb[4];
        #pragma unroll
        for (int n = 0; n < 4; n++){
            u32x2 t; t[0] = bf16pack(p[n][0], p[n][1]); t[1] = bf16pack(p[n][2], p[n][3]);
            pb[n] = __builtin_bit_cast(s16x4, t);
        }
        #pragma unroll
        for (int h16 = 0; h16 < 4; h16++){
            int r = h16 * 16 + lr;
            const unsigned short* va = &Vlds[cur][r * 64];
            #pragma unroll
            for (int sl = 0; sl < 4; sl++){
                s16x4 fv = *(const s16x4*)(va + (((sl * 2 + (lg >> 1)) ^ (r & 7)) * 8) + (lg & 1) * 4);
                acc[h16] = __builtin_amdgcn_mfma_f32_16x16x16bf16_1k(fv, pb[sl], acc[h16], 0, 0, 0);
            }
        }
        __syncthreads();
        cur ^= 1;
    }
    float inv = 1.0f / lrun;
    #pragma unroll
    for (int h16 = 0; h16 < 4; h16++){
        f32x4 o = acc[h16] * inv;
        *(f32x4*)(out + (size_t)(b * 2048 + tw + lr) * 64 + h16 * 16 + lg * 4) = o;
    }
}

extern "C" void kernel_launch(void* const* d_in, const int* in_sizes, int n_in,
                              void* d_out, int out_size, void* d_ws, size_t ws_size,
                              hipStream_t stream) {
    const float* x  = (const float*)d_in[0];
    const float* Wk = (const float*)d_in[1];
    const float* Wq = (const float*)d_in[2];
    const float* Wv = (const float*)d_in[3];
    float* out = (float*)d_out;
    char* ws = (char*)d_ws;
    if (ws_size < (size_t)7 * 1024 * 1024) return;
    unsigned short* WT = (unsigned short*)(ws);              // 384 KB
    unsigned short* kb = (unsigned short*)(ws + (1u << 20)); // 2 MB (k * 0.125*log2e)
    unsigned short* qb = (unsigned short*)(ws + (3u << 20)); // 2 MB
    unsigned short* vT = (unsigned short*)(ws + (5u << 20)); // 2 MB ([b][h][t])
    hipLaunchKernelGGL(wprep_kernel, dim3(16, 3), dim3(256), 0, stream, Wk, Wq, Wv, WT);
    hipLaunchKernelGGL(proj_kernel, dim3(512), dim3(256), 0, stream, x, WT, kb, qb, vT);
    // attn partial buffers: accp = (NS-1) x 4MB at +7MB; ml after accp
    if (ws_size >= (size_t)20 * 1024 * 1024){
        float* accp = (float*)(ws + ((size_t)7 << 20));                      // 12 MB (3 arrays)
        float* ml   = (float*)(ws + ((size_t)19 << 20));                     // 512 KB
        hipLaunchKernelGGL((attn_part_kernel<4>), dim3(1024), dim3(256), 0, stream,
                           kb, qb, vT, out, accp, ml);
        hipLaunchKernelGGL((attn_merge_kernel<4>), dim3(256), dim3(256), 0, stream,
                           accp, ml, out);
    } else if (ws_size >= (size_t)12 * 1024 * 1024){
        float* accp = (float*)(ws + ((size_t)7 << 20));                      // 4 MB (1 array)
        float* ml   = (float*)(ws + ((size_t)11 << 20));                     // 256 KB
        hipLaunchKernelGGL((attn_part_kernel<2>), dim3(512), dim3(256), 0, stream,
                           kb, qb, vT, out, accp, ml);
        hipLaunchKernelGGL((attn_merge_kernel<2>), dim3(256), dim3(256), 0, stream,
                           accp, ml, out);
    } else {
        hipLaunchKernelGGL(attn_kernel, dim3(256), dim3(256), 0, stream, kb, qb, vT, out);
    }
}

// Round 19
// 53.585 us; speedup vs baseline: 1.0223x; 1.0223x over previous
//
#include <hip/hip_runtime.h>
#include <hip/hip_bf16.h>
#include <stdint.h>

// Shapes: B=8, T=2048, E=1024, H=64
// wei[t][s] = k[t]·q[s] * 0.125 (k plays "query"), causal s<=t.
// 0.125*log2(e) folded into Wk so softmax uses exp2 directly.

typedef __attribute__((ext_vector_type(4))) float f32x4;
typedef __attribute__((ext_vector_type(4))) short s16x4;
typedef __attribute__((ext_vector_type(8))) short s16x8;
typedef __attribute__((ext_vector_type(2))) unsigned int u32x2;
typedef __attribute__((ext_vector_type(4))) unsigned int u32x4;

__device__ __forceinline__ unsigned bf16pack(float a, float b){
    unsigned ua = __builtin_bit_cast(unsigned, a);
    unsigned ub = __builtin_bit_cast(unsigned, b);
    return ((ua + 0x8000u) >> 16) | ((ub + 0x8000u) & 0xffff0000u);
}
__device__ __forceinline__ unsigned short bf16one(float a){
    return (unsigned short)((__builtin_bit_cast(unsigned, a) + 0x8000u) >> 16);
}
// async global->LDS DMA, 16B per lane; LDS dest = uniform base + lane*16 (linear)
__device__ __forceinline__ void gload16(const void* g, unsigned short* l){
    __builtin_amdgcn_global_load_lds((const __attribute__((address_space(1))) unsigned int*)g,
                                     (__attribute__((address_space(3))) unsigned int*)l, 16, 0, 0);
}

// ---------------- W prep v2 (passed r17): coalesced 64x64-tile transpose, 48 blocks ----------------
__global__ __launch_bounds__(256) void wprep_kernel(const float* __restrict__ Wk,
                                                    const float* __restrict__ Wq,
                                                    const float* __restrict__ Wv,
                                                    unsigned short* __restrict__ WT){
    __shared__ unsigned short lt[64][66];  // padded: column reads spread across banks
    int w = blockIdx.y;            // matrix 0..2
    int tr = blockIdx.x;           // k-tile 0..15
    const float* src = (w == 0) ? Wk : (w == 1) ? Wq : Wv;
    float scale = (w == 0) ? 0.18033688011112042f : 1.0f;  // 0.125 * log2(e)
    int tid = threadIdx.x;
    int row = tid >> 2, seg = tid & 3;
    const float* g = src + (size_t)(tr * 64 + row) * 64 + seg * 16;
    unsigned short* ld = &lt[row][seg * 16];
    #pragma unroll
    for (int c = 0; c < 4; c++){
        f32x4 v = *(const f32x4*)(g + c * 4);
        u32x2 pk;
        pk[0] = bf16pack(v[0] * scale, v[1] * scale);
        pk[1] = bf16pack(v[2] * scale, v[3] * scale);
        *(u32x2*)(ld + c * 4) = pk;
    }
    __syncthreads();
    int n = tid >> 2, ks = tid & 3;
    s16x8 o0, o1;
    #pragma unroll
    for (int e = 0; e < 8; e++){
        o0[e] = (short)lt[ks * 16 + e][n];
        o1[e] = (short)lt[ks * 16 + 8 + e][n];
    }
    unsigned short* dst = WT + (size_t)(w * 64 + n) * 1024 + tr * 64 + ks * 16;
    *(s16x8*)(dst)     = o0;
    *(s16x8*)(dst + 8) = o1;
}

// ---------------- Projections v10 (passed r9-r17): full DMA staging, 512x256 ----------------
__global__ __launch_bounds__(256) void proj_kernel(const float* __restrict__ x,
                                                   const unsigned short* __restrict__ WT,
                                                   unsigned short* __restrict__ kb,
                                                   unsigned short* __restrict__ qb,
                                                   unsigned short* __restrict__ vT){
    __shared__ unsigned short smem[32768];  // xb: 0/4096 (8KB each); wb: 8192/20480 (24KB each)
    int tid = threadIdx.x; int l = tid & 63; int w = tid >> 6;
    int lr = l & 15, lg = l >> 4;
    int row0 = blockIdx.x * 32;
    int b = row0 >> 11, t0 = row0 & 2047;
    const float* xbase = x + (size_t)row0 * 1024;

    auto stage = [&](int k0, int buf){
        #pragma unroll
        for (int t = 0; t < 2; t++){
            int i = w * 2 + t;
            int r = i * 4 + (l >> 4);
            int c = l & 15;
            gload16(xbase + (size_t)r * 1024 + k0 + ((c ^ ((r & 7) << 1)) * 4),
                    smem + buf * 4096 + i * 512);
        }
        #pragma unroll
        for (int u = 0; u < 6; u++){
            int i = w * 6 + u;
            int r = i * 8 + (l >> 3);
            int c = l & 7;
            gload16(WT + (size_t)r * 1024 + k0 + ((c ^ (r & 7)) * 8),
                    smem + 8192 + buf * 12288 + i * 512);
        }
    };

    f32x4 acc[2][3] = {};
    stage(0, 0);
    __syncthreads();
    int cur = 0;
    for (int k0 = 0; k0 < 1024; k0 += 64){
        int kn = (k0 + 64 < 1024) ? (k0 + 64) : 960;
        stage(kn, cur ^ 1);
        s16x8 af[2][2];
        #pragma unroll
        for (int mf = 0; mf < 2; mf++){
            int r = mf * 16 + lr;
            const unsigned short* xrow = smem + cur * 4096 + r * 128;
            #pragma unroll
            for (int kc = 0; kc < 2; kc++){
                int c0 = (kc * 8 + lg * 2) ^ ((r & 7) << 1);
                f32x4 v0 = *(const f32x4*)(xrow + c0 * 8);
                f32x4 v1 = *(const f32x4*)(xrow + c0 * 8 + 8);
                u32x4 pk;
                pk[0] = bf16pack(v0[0], v0[1]); pk[1] = bf16pack(v0[2], v0[3]);
                pk[2] = bf16pack(v1[0], v1[1]); pk[3] = bf16pack(v1[2], v1[3]);
                af[mf][kc] = __builtin_bit_cast(s16x8, pk);
            }
        }
        #pragma unroll
        for (int nn = 0; nn < 3; nn++){
            int r = (w * 3 + nn) * 16 + lr;
            const unsigned short* wrow = smem + 8192 + cur * 12288 + r * 64;
            s16x8 b0 = *(const s16x8*)(wrow + ((lg       ^ (r & 7)) * 8));
            s16x8 b1 = *(const s16x8*)(wrow + (((4 + lg) ^ (r & 7)) * 8));
            acc[0][nn] = __builtin_amdgcn_mfma_f32_16x16x32_bf16(af[0][0], b0, acc[0][nn], 0, 0, 0);
            acc[0][nn] = __builtin_amdgcn_mfma_f32_16x16x32_bf16(af[0][1], b1, acc[0][nn], 0, 0, 0);
            acc[1][nn] = __builtin_amdgcn_mfma_f32_16x16x32_bf16(af[1][0], b0, acc[1][nn], 0, 0, 0);
            acc[1][nn] = __builtin_amdgcn_mfma_f32_16x16x32_bf16(af[1][1], b1, acc[1][nn], 0, 0, 0);
        }
        __syncthreads();
        cur ^= 1;
    }
    #pragma unroll
    for (int mf = 0; mf < 2; mf++)
        #pragma unroll
        for (int nn = 0; nn < 3; nn++){
            int col = (w * 3 + nn) * 16 + lr;
            int row = mf * 16 + lg * 4;
            #pragma unroll
            for (int r = 0; r < 4; r++)
                smem[(row + r) * 200 + col] = bf16one(acc[mf][nn][r]);
        }
    __syncthreads();
    {
        int r2 = tid >> 3, c2 = (tid & 7) * 16;
        const unsigned short* srowp = smem + r2 * 200 + c2;
        unsigned short* dst = (c2 < 64)
            ? kb + (size_t)(b * 2048 + t0 + r2) * 64 + c2
            : qb + (size_t)(b * 2048 + t0 + r2) * 64 + (c2 - 64);
        *(s16x8*)(dst)     = *(const s16x8*)(srowp);
        *(s16x8*)(dst + 8) = *(const s16x8*)(srowp + 8);
        int h = tid >> 2, q3 = tid & 3;
        s16x8 vv;
        #pragma unroll
        for (int e = 0; e < 8; e++)
            vv[e] = smem[(q3 * 8 + e) * 200 + 128 + h];
        *(s16x8*)(vT + (size_t)(b * 64 + h) * 2048 + t0 + q3 * 8) = vv;
    }
}

// ---------------- attn phase A (r17 64-s body, passed @48.0): balanced strip jobs ----------------
// grid 8*32*NS: b = bx&7 (XCD-pinned); r = bx>>3: bt = 31 - r/NS (heavy first), strip = r%NS.
template<int NS>
__global__ __launch_bounds__(256) void attn_part_kernel(const unsigned short* __restrict__ kb,
                                                        const unsigned short* __restrict__ qb,
                                                        const unsigned short* __restrict__ vT,
                                                        float* __restrict__ out,
                                                        float* __restrict__ accp,
                                                        float* __restrict__ ml){
    __shared__ unsigned short Klds[2][64 * 64];
    __shared__ unsigned short Vlds[2][64 * 64];
    int tid = threadIdx.x; int l = tid & 63; int w = tid >> 6;
    int lr = l & 15, lg = l >> 4;
    int bx = blockIdx.x;
    int b = bx & 7;
    int r9 = bx >> 3;
    int bt = 31 - (r9 / NS);
    int strip = r9 % NS;
    int t0 = bt * 64;
    int tw = t0 + w * 16;
    const unsigned short* fqp = kb + (size_t)(b * 2048 + tw + lr) * 64 + lg * 8;
    s16x8 fq0 = *(const s16x8*)(fqp);
    s16x8 fq1 = *(const s16x8*)(fqp + 32);
    const unsigned short* qbb = qb + (size_t)b * 2048 * 64;
    const unsigned short* vbb = vT + (size_t)b * 64 * 2048;

    int srhi = l >> 3;
    int schk = l & 7;
    f32x4 acc[4] = {};
    float mrun = -3.0e38f, lrun = 0.0f;

    {
        int s0 = strip * 64;   // in-bounds for all strips (<= 448 + 63 < 2048)
        #pragma unroll
        for (int t = 0; t < 2; t++){
            int ti = w * 2 + t;
            int row = ti * 8 + srhi;
            gload16(qbb + (size_t)(s0 + row) * 64 + ((schk ^ (row & 7)) * 8), &Klds[0][ti * 512]);
            gload16(vbb + (size_t)row * 2048 + s0 + ((schk ^ (row & 7)) * 8), &Vlds[0][ti * 512]);
        }
    }
    __syncthreads();
    int cur = 0;
    for (int c = strip; c <= bt; c += NS){
        int nc = (c + NS <= bt) ? (c + NS) : c;
        int ns0 = nc * 64;
        #pragma unroll
        for (int t = 0; t < 2; t++){
            int ti = w * 2 + t;
            int row = ti * 8 + srhi;
            gload16(qbb + (size_t)(ns0 + row) * 64 + ((schk ^ (row & 7)) * 8), &Klds[cur ^ 1][ti * 512]);
            gload16(vbb + (size_t)row * 2048 + ns0 + ((schk ^ (row & 7)) * 8), &Vlds[cur ^ 1][ti * 512]);
        }
        f32x4 Cs[4];
        #pragma unroll
        for (int n = 0; n < 4; n++){
            int r = n * 16 + lr;
            const unsigned short* ka = &Klds[cur][r * 64];
            s16x8 k0 = *(const s16x8*)(ka + ((lg       ^ (r & 7)) * 8));
            s16x8 k1 = *(const s16x8*)(ka + (((4 + lg) ^ (r & 7)) * 8));
            f32x4 z = {};
            z     = __builtin_amdgcn_mfma_f32_16x16x32_bf16(k0, fq0, z, 0, 0, 0);
            Cs[n] = __builtin_amdgcn_mfma_f32_16x16x32_bf16(k1, fq1, z, 0, 0, 0);
        }
        if (c == bt){  // diagonal chunk: mask s>t
            #pragma unroll
            for (int n = 0; n < 4; n++)
                #pragma unroll
                for (int r = 0; r < 4; r++)
                    if (n * 16 + lg * 4 + r > w * 16 + lr) Cs[n][r] = -3.0e38f;
        }
        float pm = -3.0e38f;
        #pragma unroll
        for (int n = 0; n < 4; n++)
            #pragma unroll
            for (int r = 0; r < 4; r++) pm = fmaxf(pm, Cs[n][r]);
        pm = fmaxf(pm, __shfl_xor(pm, 16));
        pm = fmaxf(pm, __shfl_xor(pm, 32));
        // exact defer-rescale: skip O(acc) rescale while exp2(C-m~) <= 2^8 stays bounded
        float mnew;
        if (__all(pm <= mrun + 8.0f)){
            mnew = mrun;
        } else {
            mnew = fmaxf(mrun, pm);
            float scl = exp2f(mrun - mnew);
            lrun *= scl;
            #pragma unroll
            for (int h16 = 0; h16 < 4; h16++) acc[h16] *= scl;
        }
        float p[4][4]; float ps = 0.0f;
        #pragma unroll
        for (int n = 0; n < 4; n++)
            #pragma unroll
            for (int r = 0; r < 4; r++){ float e = exp2f(Cs[n][r] - mnew); p[n][r] = e; ps += e; }
        ps += __shfl_xor(ps, 16);
        ps += __shfl_xor(ps, 32);
        lrun += ps;
        mrun = mnew;
        s16x4 pb[4];
        #pragma unroll
        for (int n = 0; n < 4; n++){
            u32x2 t; t[0] = bf16pack(p[n][0], p[n][1]); t[1] = bf16pack(p[n][2], p[n][3]);
            pb[n] = __builtin_bit_cast(s16x4, t);
        }
        #pragma unroll
        for (int h16 = 0; h16 < 4; h16++){
            int r = h16 * 16 + lr;
            const unsigned short* va = &Vlds[cur][r * 64];
            #pragma unroll
            for (int sl = 0; sl < 4; sl++){
                s16x4 fv = *(const s16x4*)(va + (((sl * 2 + (lg >> 1)) ^ (r & 7)) * 8) + (lg & 1) * 4);
                acc[h16] = __builtin_amdgcn_mfma_f32_16x16x16bf16_1k(fv, pb[sl], acc[h16], 0, 0, 0);
            }
        }
        __syncthreads();
        cur ^= 1;
    }
    float* accdst = (strip == 0) ? out : (accp + (size_t)(strip - 1) * (8 * 2048 * 64));
    #pragma unroll
    for (int h16 = 0; h16 < 4; h16++)
        *(f32x4*)(accdst + (size_t)(b * 2048 + tw + lr) * 64 + h16 * 16 + lg * 4) = acc[h16];
    if (lg == 0){
        int idx = ((strip * 8 + b) * 32 + bt) * 64 + w * 16 + lr;
        ml[idx * 2]     = mrun;
        ml[idx * 2 + 1] = lrun;
    }
}

// ---------------- attn phase B: merge NS strips per tile (XCD-aligned grid) ----------------
template<int NS>
__global__ __launch_bounds__(256) void attn_merge_kernel(const float* __restrict__ accp,
                                                         const float* __restrict__ ml,
                                                         float* __restrict__ out){
    int bx = blockIdx.x;
    int b = bx & 7, bt = bx >> 3;
    int tid = threadIdx.x;
    int row = tid >> 2, cg = (tid & 3) * 16;
    float m[NS], lv[NS];
    float mg = -3.0e38f;
    #pragma unroll
    for (int s = 0; s < NS; s++){
        int idx = (((s * 8 + b) * 32 + bt) * 64 + row) * 2;
        m[s] = ml[idx]; lv[s] = ml[idx + 1];
        mg = fmaxf(mg, m[s]);
    }
    float wt[NS]; float lt = 0.0f;
    #pragma unroll
    for (int s = 0; s < NS; s++){ wt[s] = exp2f(m[s] - mg); lt += lv[s] * wt[s]; }
    float inv = 1.0f / lt;
    size_t base = (size_t)(b * 2048 + bt * 64 + row) * 64 + cg;
    #pragma unroll
    for (int g = 0; g < 4; g++){
        f32x4 o = (*(const f32x4*)(out + base + g * 4)) * wt[0];
        #pragma unroll
        for (int s = 1; s < NS; s++)
            o += (*(const f32x4*)(accp + (size_t)(s - 1) * (8 * 2048 * 64) + base + g * 4)) * wt[s];
        o *= inv;
        *(f32x4*)(out + base + g * 4) = o;
    }
}

// ---------------- Flash attention v8 (fallback if ws too small; passed r8/r9) ----------------
__global__ __launch_bounds__(256) void attn_kernel(const unsigned short* __restrict__ kb,
                                                   const unsigned short* __restrict__ qb,
                                                   const unsigned short* __restrict__ vT,
                                                   float* __restrict__ out){
    __shared__ unsigned short Klds[2][64 * 64];
    __shared__ unsigned short Vlds[2][64 * 64];
    int tid = threadIdx.x; int l = tid & 63; int w = tid >> 6;
    int lr = l & 15, lg = l >> 4;
    int bx = blockIdx.x;
    int b = bx & 7;
    int bt = bx >> 3;
    int t0 = bt * 64;
    int tw = t0 + w * 16;
    const unsigned short* fqp = kb + (size_t)(b * 2048 + tw + lr) * 64 + lg * 8;
    s16x8 fq0 = *(const s16x8*)(fqp);
    s16x8 fq1 = *(const s16x8*)(fqp + 32);
    const unsigned short* qbb = qb + (size_t)b * 2048 * 64;
    const unsigned short* vbb = vT + (size_t)b * 64 * 2048;
    int srhi = l >> 3;
    int schk = l & 7;
    f32x4 acc[4] = {};
    float mrun = -3.0e38f, lrun = 0.0f;
    #pragma unroll
    for (int t = 0; t < 2; t++){
        int ti = w * 2 + t;
        int row = ti * 8 + srhi;
        gload16(qbb + (size_t)row * 64 + ((schk ^ (row & 7)) * 8), &Klds[0][ti * 512]);
        gload16(vbb + (size_t)row * 2048 + ((schk ^ (row & 7)) * 8), &Vlds[0][ti * 512]);
    }
    __syncthreads();
    int cur = 0;
    for (int c = 0; c <= bt; ++c){
        int nc = (c + 1 <= bt) ? (c + 1) : bt;
        int ns0 = nc * 64;
        #pragma unroll
        for (int t = 0; t < 2; t++){
            int ti = w * 2 + t;
            int row = ti * 8 + srhi;
            gload16(qbb + (size_t)(ns0 + row) * 64 + ((schk ^ (row & 7)) * 8), &Klds[cur ^ 1][ti * 512]);
            gload16(vbb + (size_t)row * 2048 + ns0 + ((schk ^ (row & 7)) * 8), &Vlds[cur ^ 1][ti * 512]);
        }
        f32x4 Cs[4];
        #pragma unroll
        for (int n = 0; n < 4; n++){
            int r = n * 16 + lr;
            const unsigned short* ka = &Klds[cur][r * 64];
            s16x8 k0 = *(const s16x8*)(ka + ((lg       ^ (r & 7)) * 8));
            s16x8 k1 = *(const s16x8*)(ka + (((4 + lg) ^ (r & 7)) * 8));
            f32x4 z = {};
            z     = __builtin_amdgcn_mfma_f32_16x16x32_bf16(k0, fq0, z, 0, 0, 0);
            Cs[n] = __builtin_amdgcn_mfma_f32_16x16x32_bf16(k1, fq1, z, 0, 0, 0);
        }
        if (c == bt){
            #pragma unroll
            for (int n = 0; n < 4; n++)
                #pragma unroll
                for (int r = 0; r < 4; r++)
                    if (n * 16 + lg * 4 + r > w * 16 + lr) Cs[n][r] = -3.0e38f;
        }
        float pm = -3.0e38f;
        #pragma unroll
        for (int n = 0; n < 4; n++)
            #pragma unroll
            for (int r = 0; r < 4; r++) pm = fmaxf(pm, Cs[n][r]);
        pm = fmaxf(pm, __shfl_xor(pm, 16));
        pm = fmaxf(pm, __shfl_xor(pm, 32));
        float mnew = fmaxf(mrun, pm);
        float scl = exp2f(mrun - mnew);
        float p[4][4]; float ps = 0.0f;
        #pragma unroll
        for (int n = 0; n < 4; n++)
            #pragma unroll
            for (int r = 0; r < 4; r++){ float e = exp2f(Cs[n][r] - mnew); p[n][r] = e; ps += e; }
        ps += __shfl_xor(ps, 16);
        ps += __shfl_xor(ps, 32);
        lrun = lrun * scl + ps;
        mrun = mnew;
        #pragma unroll
        for (int h16 = 0; h16 < 4; h16++) acc[h16] *= scl;
        s16x4 pb[4];
        #pragma unroll
        for (int n = 0; n < 4; n++){
            u32x2 t; t[0] = bf16pack(p[n][0], p[n][1]); t[1] = bf16pack(p[n][2], p[n][3]);
            pb[n] = __builtin_bit_cast(s16x4, t);
        }
        #pragma unroll
        for (int h16 = 0; h16 < 4; h16++){
            int r = h16 * 16 + lr;
            const unsigned short* va = &Vlds[cur][r * 64];
            #pragma unroll
            for (int sl = 0; sl < 4; sl++){
                s16x4 fv = *(const s16x4*)(va + (((sl * 2 + (lg >> 1)) ^ (r & 7)) * 8) + (lg & 1) * 4);
                acc[h16] = __builtin_amdgcn_mfma_f32_16x16x16bf16_1k(fv, pb[sl], acc[h16], 0, 0, 0);
            }
        }
        __syncthreads();
        cur ^= 1;
    }
    float inv = 1.0f / lrun;
    #pragma unroll
    for (int h16 = 0; h16 < 4; h16++){
        f32x4 o = acc[h16] * inv;
        *(f32x4*)(out + (size_t)(b * 2048 + tw + lr) * 64 + h16 * 16 + lg * 4) = o;
    }
}

extern "C" void kernel_launch(void* const* d_in, const int* in_sizes, int n_in,
                              void* d_out, int out_size, void* d_ws, size_t ws_size,
                              hipStream_t stream) {
    const float* x  = (const float*)d_in[0];
    const float* Wk = (const float*)d_in[1];
    const float* Wq = (const float*)d_in[2];
    const float* Wv = (const float*)d_in[3];
    float* out = (float*)d_out;
    char* ws = (char*)d_ws;
    if (ws_size < (size_t)7 * 1024 * 1024) return;
    unsigned short* WT = (unsigned short*)(ws);              // 384 KB
    unsigned short* kb = (unsigned short*)(ws + (1u << 20)); // 2 MB (k * 0.125*log2e)
    unsigned short* qb = (unsigned short*)(ws + (3u << 20)); // 2 MB
    unsigned short* vT = (unsigned short*)(ws + (5u << 20)); // 2 MB ([b][h][t])
    hipLaunchKernelGGL(wprep_kernel, dim3(16, 3), dim3(256), 0, stream, Wk, Wq, Wv, WT);
    hipLaunchKernelGGL(proj_kernel, dim3(512), dim3(256), 0, stream, x, WT, kb, qb, vT);
    // attn partial buffers: accp = (NS-1) x 4MB at +7MB; ml after accp
    if (ws_size >= (size_t)37 * 1024 * 1024){
        float* accp = (float*)(ws + ((size_t)7 << 20));                      // 28 MB (7 arrays)
        float* ml   = (float*)(ws + ((size_t)35 << 20));                     // 1 MB
        hipLaunchKernelGGL((attn_part_kernel<8>), dim3(2048), dim3(256), 0, stream,
                           kb, qb, vT, out, accp, ml);
        hipLaunchKernelGGL((attn_merge_kernel<8>), dim3(256), dim3(256), 0, stream,
                           accp, ml, out);
    } else if (ws_size >= (size_t)20 * 1024 * 1024){
        float* accp = (float*)(ws + ((size_t)7 << 20));                      // 12 MB (3 arrays)
        float* ml   = (float*)(ws + ((size_t)19 << 20));                     // 512 KB
        hipLaunchKernelGGL((attn_part_kernel<4>), dim3(1024), dim3(256), 0, stream,
                           kb, qb, vT, out, accp, ml);
        hipLaunchKernelGGL((attn_merge_kernel<4>), dim3(256), dim3(256), 0, stream,
                           accp, ml, out);
    } else if (ws_size >= (size_t)12 * 1024 * 1024){
        float* accp = (float*)(ws + ((size_t)7 << 20));                      // 4 MB (1 array)
        float* ml   = (float*)(ws + ((size_t)11 << 20));                     // 256 KB
        hipLaunchKernelGGL((attn_part_kernel<2>), dim3(512), dim3(256), 0, stream,
                           kb, qb, vT, out, accp, ml);
        hipLaunchKernelGGL((attn_merge_kernel<2>), dim3(256), dim3(256), 0, stream,
                           accp, ml, out);
    } else {
        hipLaunchKernelGGL(attn_kernel, dim3(256), dim3(256), 0, stream, kb, qb, vT, out);
    }
}

// Round 20
// 47.597 us; speedup vs baseline: 1.1509x; 1.1258x over previous
//
#include <hip/hip_runtime.h>
#include <hip/hip_bf16.h>
#include <stdint.h>

// Shapes: B=8, T=2048, E=1024, H=64
// wei[t][s] = k[t]·q[s] * 0.125 (k plays "query"), causal s<=t.
// 0.125*log2(e) folded into Wk so softmax uses exp2 directly.

typedef __attribute__((ext_vector_type(4))) float f32x4;
typedef __attribute__((ext_vector_type(4))) short s16x4;
typedef __attribute__((ext_vector_type(8))) short s16x8;
typedef __attribute__((ext_vector_type(2))) unsigned int u32x2;
typedef __attribute__((ext_vector_type(4))) unsigned int u32x4;

__device__ __forceinline__ unsigned bf16pack(float a, float b){
    unsigned ua = __builtin_bit_cast(unsigned, a);
    unsigned ub = __builtin_bit_cast(unsigned, b);
    return ((ua + 0x8000u) >> 16) | ((ub + 0x8000u) & 0xffff0000u);
}
__device__ __forceinline__ unsigned short bf16one(float a){
    return (unsigned short)((__builtin_bit_cast(unsigned, a) + 0x8000u) >> 16);
}
// async global->LDS DMA, 16B per lane; LDS dest = uniform base + lane*16 (linear)
__device__ __forceinline__ void gload16(const void* g, unsigned short* l){
    __builtin_amdgcn_global_load_lds((const __attribute__((address_space(1))) unsigned int*)g,
                                     (__attribute__((address_space(3))) unsigned int*)l, 16, 0, 0);
}

// ---------------- W prep v2 (passed r17): coalesced 64x64-tile transpose, 48 blocks ----------------
__global__ __launch_bounds__(256) void wprep_kernel(const float* __restrict__ Wk,
                                                    const float* __restrict__ Wq,
                                                    const float* __restrict__ Wv,
                                                    unsigned short* __restrict__ WT){
    __shared__ unsigned short lt[64][66];  // padded: column reads spread across banks
    int w = blockIdx.y;            // matrix 0..2
    int tr = blockIdx.x;           // k-tile 0..15
    const float* src = (w == 0) ? Wk : (w == 1) ? Wq : Wv;
    float scale = (w == 0) ? 0.18033688011112042f : 1.0f;  // 0.125 * log2(e)
    int tid = threadIdx.x;
    int row = tid >> 2, seg = tid & 3;
    const float* g = src + (size_t)(tr * 64 + row) * 64 + seg * 16;
    unsigned short* ld = &lt[row][seg * 16];
    #pragma unroll
    for (int c = 0; c < 4; c++){
        f32x4 v = *(const f32x4*)(g + c * 4);
        u32x2 pk;
        pk[0] = bf16pack(v[0] * scale, v[1] * scale);
        pk[1] = bf16pack(v[2] * scale, v[3] * scale);
        *(u32x2*)(ld + c * 4) = pk;
    }
    __syncthreads();
    int n = tid >> 2, ks = tid & 3;
    s16x8 o0, o1;
    #pragma unroll
    for (int e = 0; e < 8; e++){
        o0[e] = (short)lt[ks * 16 + e][n];
        o1[e] = (short)lt[ks * 16 + 8 + e][n];
    }
    unsigned short* dst = WT + (size_t)(w * 64 + n) * 1024 + tr * 64 + ks * 16;
    *(s16x8*)(dst)     = o0;
    *(s16x8*)(dst + 8) = o1;
}

// ---------------- Projections v10 (passed r9-r17): full DMA staging, 512x256 ----------------
__global__ __launch_bounds__(256) void proj_kernel(const float* __restrict__ x,
                                                   const unsigned short* __restrict__ WT,
                                                   unsigned short* __restrict__ kb,
                                                   unsigned short* __restrict__ qb,
                                                   unsigned short* __restrict__ vT){
    __shared__ unsigned short smem[32768];  // xb: 0/4096 (8KB each); wb: 8192/20480 (24KB each)
    int tid = threadIdx.x; int l = tid & 63; int w = tid >> 6;
    int lr = l & 15, lg = l >> 4;
    int row0 = blockIdx.x * 32;
    int b = row0 >> 11, t0 = row0 & 2047;
    const float* xbase = x + (size_t)row0 * 1024;

    auto stage = [&](int k0, int buf){
        #pragma unroll
        for (int t = 0; t < 2; t++){
            int i = w * 2 + t;
            int r = i * 4 + (l >> 4);
            int c = l & 15;
            gload16(xbase + (size_t)r * 1024 + k0 + ((c ^ ((r & 7) << 1)) * 4),
                    smem + buf * 4096 + i * 512);
        }
        #pragma unroll
        for (int u = 0; u < 6; u++){
            int i = w * 6 + u;
            int r = i * 8 + (l >> 3);
            int c = l & 7;
            gload16(WT + (size_t)r * 1024 + k0 + ((c ^ (r & 7)) * 8),
                    smem + 8192 + buf * 12288 + i * 512);
        }
    };

    f32x4 acc[2][3] = {};
    stage(0, 0);
    __syncthreads();
    int cur = 0;
    for (int k0 = 0; k0 < 1024; k0 += 64){
        int kn = (k0 + 64 < 1024) ? (k0 + 64) : 960;
        stage(kn, cur ^ 1);
        s16x8 af[2][2];
        #pragma unroll
        for (int mf = 0; mf < 2; mf++){
            int r = mf * 16 + lr;
            const unsigned short* xrow = smem + cur * 4096 + r * 128;
            #pragma unroll
            for (int kc = 0; kc < 2; kc++){
                int c0 = (kc * 8 + lg * 2) ^ ((r & 7) << 1);
                f32x4 v0 = *(const f32x4*)(xrow + c0 * 8);
                f32x4 v1 = *(const f32x4*)(xrow + c0 * 8 + 8);
                u32x4 pk;
                pk[0] = bf16pack(v0[0], v0[1]); pk[1] = bf16pack(v0[2], v0[3]);
                pk[2] = bf16pack(v1[0], v1[1]); pk[3] = bf16pack(v1[2], v1[3]);
                af[mf][kc] = __builtin_bit_cast(s16x8, pk);
            }
        }
        #pragma unroll
        for (int nn = 0; nn < 3; nn++){
            int r = (w * 3 + nn) * 16 + lr;
            const unsigned short* wrow = smem + 8192 + cur * 12288 + r * 64;
            s16x8 b0 = *(const s16x8*)(wrow + ((lg       ^ (r & 7)) * 8));
            s16x8 b1 = *(const s16x8*)(wrow + (((4 + lg) ^ (r & 7)) * 8));
            acc[0][nn] = __builtin_amdgcn_mfma_f32_16x16x32_bf16(af[0][0], b0, acc[0][nn], 0, 0, 0);
            acc[0][nn] = __builtin_amdgcn_mfma_f32_16x16x32_bf16(af[0][1], b1, acc[0][nn], 0, 0, 0);
            acc[1][nn] = __builtin_amdgcn_mfma_f32_16x16x32_bf16(af[1][0], b0, acc[1][nn], 0, 0, 0);
            acc[1][nn] = __builtin_amdgcn_mfma_f32_16x16x32_bf16(af[1][1], b1, acc[1][nn], 0, 0, 0);
        }
        __syncthreads();
        cur ^= 1;
    }
    #pragma unroll
    for (int mf = 0; mf < 2; mf++)
        #pragma unroll
        for (int nn = 0; nn < 3; nn++){
            int col = (w * 3 + nn) * 16 + lr;
            int row = mf * 16 + lg * 4;
            #pragma unroll
            for (int r = 0; r < 4; r++)
                smem[(row + r) * 200 + col] = bf16one(acc[mf][nn][r]);
        }
    __syncthreads();
    {
        int r2 = tid >> 3, c2 = (tid & 7) * 16;
        const unsigned short* srowp = smem + r2 * 200 + c2;
        unsigned short* dst = (c2 < 64)
            ? kb + (size_t)(b * 2048 + t0 + r2) * 64 + c2
            : qb + (size_t)(b * 2048 + t0 + r2) * 64 + (c2 - 64);
        *(s16x8*)(dst)     = *(const s16x8*)(srowp);
        *(s16x8*)(dst + 8) = *(const s16x8*)(srowp + 8);
        int h = tid >> 2, q3 = tid & 3;
        s16x8 vv;
        #pragma unroll
        for (int e = 0; e < 8; e++)
            vv[e] = smem[(q3 * 8 + e) * 200 + 128 + h];
        *(s16x8*)(vT + (size_t)(b * 64 + h) * 2048 + t0 + q3 * 8) = vv;
    }
}

// ---------------- attn phase A (r17 64-s body, passed @48.0): balanced strip jobs ----------------
// grid 8*32*NS: b = bx&7 (XCD-pinned); r = bx>>3: bt = 31 - r/NS (heavy first), strip = r%NS.
template<int NS>
__global__ __launch_bounds__(256) void attn_part_kernel(const unsigned short* __restrict__ kb,
                                                        const unsigned short* __restrict__ qb,
                                                        const unsigned short* __restrict__ vT,
                                                        float* __restrict__ out,
                                                        float* __restrict__ accp,
                                                        float* __restrict__ ml){
    __shared__ unsigned short Klds[2][64 * 64];
    __shared__ unsigned short Vlds[2][64 * 64];
    int tid = threadIdx.x; int l = tid & 63; int w = tid >> 6;
    int lr = l & 15, lg = l >> 4;
    int bx = blockIdx.x;
    int b = bx & 7;
    int r9 = bx >> 3;
    int bt = 31 - (r9 / NS);
    int strip = r9 % NS;
    int t0 = bt * 64;
    int tw = t0 + w * 16;
    const unsigned short* fqp = kb + (size_t)(b * 2048 + tw + lr) * 64 + lg * 8;
    s16x8 fq0 = *(const s16x8*)(fqp);
    s16x8 fq1 = *(const s16x8*)(fqp + 32);
    const unsigned short* qbb = qb + (size_t)b * 2048 * 64;
    const unsigned short* vbb = vT + (size_t)b * 64 * 2048;

    int srhi = l >> 3;
    int schk = l & 7;
    f32x4 acc[4] = {};
    float mrun = -3.0e38f, lrun = 0.0f;

    {
        int s0 = strip * 64;
        #pragma unroll
        for (int t = 0; t < 2; t++){
            int ti = w * 2 + t;
            int row = ti * 8 + srhi;
            gload16(qbb + (size_t)(s0 + row) * 64 + ((schk ^ (row & 7)) * 8), &Klds[0][ti * 512]);
            gload16(vbb + (size_t)row * 2048 + s0 + ((schk ^ (row & 7)) * 8), &Vlds[0][ti * 512]);
        }
    }
    __syncthreads();
    int cur = 0;
    for (int c = strip; c <= bt; c += NS){
        int nc = (c + NS <= bt) ? (c + NS) : c;
        int ns0 = nc * 64;
        #pragma unroll
        for (int t = 0; t < 2; t++){
            int ti = w * 2 + t;
            int row = ti * 8 + srhi;
            gload16(qbb + (size_t)(ns0 + row) * 64 + ((schk ^ (row & 7)) * 8), &Klds[cur ^ 1][ti * 512]);
            gload16(vbb + (size_t)row * 2048 + ns0 + ((schk ^ (row & 7)) * 8), &Vlds[cur ^ 1][ti * 512]);
        }
        f32x4 Cs[4];
        #pragma unroll
        for (int n = 0; n < 4; n++){
            int r = n * 16 + lr;
            const unsigned short* ka = &Klds[cur][r * 64];
            s16x8 k0 = *(const s16x8*)(ka + ((lg       ^ (r & 7)) * 8));
            s16x8 k1 = *(const s16x8*)(ka + (((4 + lg) ^ (r & 7)) * 8));
            f32x4 z = {};
            z     = __builtin_amdgcn_mfma_f32_16x16x32_bf16(k0, fq0, z, 0, 0, 0);
            Cs[n] = __builtin_amdgcn_mfma_f32_16x16x32_bf16(k1, fq1, z, 0, 0, 0);
        }
        if (c == bt){  // diagonal chunk: mask s>t
            #pragma unroll
            for (int n = 0; n < 4; n++)
                #pragma unroll
                for (int r = 0; r < 4; r++)
                    if (n * 16 + lg * 4 + r > w * 16 + lr) Cs[n][r] = -3.0e38f;
        }
        float pm = -3.0e38f;
        #pragma unroll
        for (int n = 0; n < 4; n++)
            #pragma unroll
            for (int r = 0; r < 4; r++) pm = fmaxf(pm, Cs[n][r]);
        pm = fmaxf(pm, __shfl_xor(pm, 16));
        pm = fmaxf(pm, __shfl_xor(pm, 32));
        // exact defer-rescale: skip O(acc) rescale while exp2(C-m~) <= 2^8 stays bounded
        float mnew;
        if (__all(pm <= mrun + 8.0f)){
            mnew = mrun;
        } else {
            mnew = fmaxf(mrun, pm);
            float scl = exp2f(mrun - mnew);
            lrun *= scl;
            #pragma unroll
            for (int h16 = 0; h16 < 4; h16++) acc[h16] *= scl;
        }
        float p[4][4]; float ps = 0.0f;
        #pragma unroll
        for (int n = 0; n < 4; n++)
            #pragma unroll
            for (int r = 0; r < 4; r++){ float e = exp2f(Cs[n][r] - mnew); p[n][r] = e; ps += e; }
        ps += __shfl_xor(ps, 16);
        ps += __shfl_xor(ps, 32);
        lrun += ps;
        mrun = mnew;
        s16x4 pb[4];
        #pragma unroll
        for (int n = 0; n < 4; n++){
            u32x2 t; t[0] = bf16pack(p[n][0], p[n][1]); t[1] = bf16pack(p[n][2], p[n][3]);
            pb[n] = __builtin_bit_cast(s16x4, t);
        }
        #pragma unroll
        for (int h16 = 0; h16 < 4; h16++){
            int r = h16 * 16 + lr;
            const unsigned short* va = &Vlds[cur][r * 64];
            #pragma unroll
            for (int sl = 0; sl < 4; sl++){
                s16x4 fv = *(const s16x4*)(va + (((sl * 2 + (lg >> 1)) ^ (r & 7)) * 8) + (lg & 1) * 4);
                acc[h16] = __builtin_amdgcn_mfma_f32_16x16x16bf16_1k(fv, pb[sl], acc[h16], 0, 0, 0);
            }
        }
        __syncthreads();
        cur ^= 1;
    }
    float* accdst = (strip == 0) ? out : (accp + (size_t)(strip - 1) * (8 * 2048 * 64));
    #pragma unroll
    for (int h16 = 0; h16 < 4; h16++)
        *(f32x4*)(accdst + (size_t)(b * 2048 + tw + lr) * 64 + h16 * 16 + lg * 4) = acc[h16];
    if (lg == 0){
        int idx = ((strip * 8 + b) * 32 + bt) * 64 + w * 16 + lr;
        ml[idx * 2]     = mrun;
        ml[idx * 2 + 1] = lrun;
    }
}

// ---------------- attn phase B: merge NS strips per tile (XCD-aligned grid) ----------------
template<int NS>
__global__ __launch_bounds__(256) void attn_merge_kernel(const float* __restrict__ accp,
                                                         const float* __restrict__ ml,
                                                         float* __restrict__ out){
    int bx = blockIdx.x;
    int b = bx & 7, bt = bx >> 3;
    int tid = threadIdx.x;
    int row = tid >> 2, cg = (tid & 3) * 16;
    float m[NS], lv[NS];
    float mg = -3.0e38f;
    #pragma unroll
    for (int s = 0; s < NS; s++){
        int idx = (((s * 8 + b) * 32 + bt) * 64 + row) * 2;
        m[s] = ml[idx]; lv[s] = ml[idx + 1];
        mg = fmaxf(mg, m[s]);
    }
    float wt[NS]; float lt = 0.0f;
    #pragma unroll
    for (int s = 0; s < NS; s++){ wt[s] = exp2f(m[s] - mg); lt += lv[s] * wt[s]; }
    float inv = 1.0f / lt;
    size_t base = (size_t)(b * 2048 + bt * 64 + row) * 64 + cg;
    #pragma unroll
    for (int g = 0; g < 4; g++){
        f32x4 o = (*(const f32x4*)(out + base + g * 4)) * wt[0];
        #pragma unroll
        for (int s = 1; s < NS; s++)
            o += (*(const f32x4*)(accp + (size_t)(s - 1) * (8 * 2048 * 64) + base + g * 4)) * wt[s];
        o *= inv;
        *(f32x4*)(out + base + g * 4) = o;
    }
}

// ---------------- Flash attention v8 (fallback if ws too small; passed r8/r9) ----------------
__global__ __launch_bounds__(256) void attn_kernel(const unsigned short* __restrict__ kb,
                                                   const unsigned short* __restrict__ qb,
                                                   const unsigned short* __restrict__ vT,
                                                   float* __restrict__ out){
    __shared__ unsigned short Klds[2][64 * 64];
    __shared__ unsigned short Vlds[2][64 * 64];
    int tid = threadIdx.x; int l = tid & 63; int w = tid >> 6;
    int lr = l & 15, lg = l >> 4;
    int bx = blockIdx.x;
    int b = bx & 7;
    int bt = bx >> 3;
    int t0 = bt * 64;
    int tw = t0 + w * 16;
    const unsigned short* fqp = kb + (size_t)(b * 2048 + tw + lr) * 64 + lg * 8;
    s16x8 fq0 = *(const s16x8*)(fqp);
    s16x8 fq1 = *(const s16x8*)(fqp + 32);
    const unsigned short* qbb = qb + (size_t)b * 2048 * 64;
    const unsigned short* vbb = vT + (size_t)b * 64 * 2048;
    int srhi = l >> 3;
    int schk = l & 7;
    f32x4 acc[4] = {};
    float mrun = -3.0e38f, lrun = 0.0f;
    #pragma unroll
    for (int t = 0; t < 2; t++){
        int ti = w * 2 + t;
        int row = ti * 8 + srhi;
        gload16(qbb + (size_t)row * 64 + ((schk ^ (row & 7)) * 8), &Klds[0][ti * 512]);
        gload16(vbb + (size_t)row * 2048 + ((schk ^ (row & 7)) * 8), &Vlds[0][ti * 512]);
    }
    __syncthreads();
    int cur = 0;
    for (int c = 0; c <= bt; ++c){
        int nc = (c + 1 <= bt) ? (c + 1) : bt;
        int ns0 = nc * 64;
        #pragma unroll
        for (int t = 0; t < 2; t++){
            int ti = w * 2 + t;
            int row = ti * 8 + srhi;
            gload16(qbb + (size_t)(ns0 + row) * 64 + ((schk ^ (row & 7)) * 8), &Klds[cur ^ 1][ti * 512]);
            gload16(vbb + (size_t)row * 2048 + ns0 + ((schk ^ (row & 7)) * 8), &Vlds[cur ^ 1][ti * 512]);
        }
        f32x4 Cs[4];
        #pragma unroll
        for (int n = 0; n < 4; n++){
            int r = n * 16 + lr;
            const unsigned short* ka = &Klds[cur][r * 64];
            s16x8 k0 = *(const s16x8*)(ka + ((lg       ^ (r & 7)) * 8));
            s16x8 k1 = *(const s16x8*)(ka + (((4 + lg) ^ (r & 7)) * 8));
            f32x4 z = {};
            z     = __builtin_amdgcn_mfma_f32_16x16x32_bf16(k0, fq0, z, 0, 0, 0);
            Cs[n] = __builtin_amdgcn_mfma_f32_16x16x32_bf16(k1, fq1, z, 0, 0, 0);
        }
        if (c == bt){
            #pragma unroll
            for (int n = 0; n < 4; n++)
                #pragma unroll
                for (int r = 0; r < 4; r++)
                    if (n * 16 + lg * 4 + r > w * 16 + lr) Cs[n][r] = -3.0e38f;
        }
        float pm = -3.0e38f;
        #pragma unroll
        for (int n = 0; n < 4; n++)
            #pragma unroll
            for (int r = 0; r < 4; r++) pm = fmaxf(pm, Cs[n][r]);
        pm = fmaxf(pm, __shfl_xor(pm, 16));
        pm = fmaxf(pm, __shfl_xor(pm, 32));
        float mnew = fmaxf(mrun, pm);
        float scl = exp2f(mrun - mnew);
        float p[4][4]; float ps = 0.0f;
        #pragma unroll
        for (int n = 0; n < 4; n++)
            #pragma unroll
            for (int r = 0; r < 4; r++){ float e = exp2f(Cs[n][r] - mnew); p[n][r] = e; ps += e; }
        ps += __shfl_xor(ps, 16);
        ps += __shfl_xor(ps, 32);
        lrun = lrun * scl + ps;
        mrun = mnew;
        #pragma unroll
        for (int h16 = 0; h16 < 4; h16++) acc[h16] *= scl;
        s16x4 pb[4];
        #pragma unroll
        for (int n = 0; n < 4; n++){
            u32x2 t; t[0] = bf16pack(p[n][0], p[n][1]); t[1] = bf16pack(p[n][2], p[n][3]);
            pb[n] = __builtin_bit_cast(s16x4, t);
        }
        #pragma unroll
        for (int h16 = 0; h16 < 4; h16++){
            int r = h16 * 16 + lr;
            const unsigned short* va = &Vlds[cur][r * 64];
            #pragma unroll
            for (int sl = 0; sl < 4; sl++){
                s16x4 fv = *(const s16x4*)(va + (((sl * 2 + (lg >> 1)) ^ (r & 7)) * 8) + (lg & 1) * 4);
                acc[h16] = __builtin_amdgcn_mfma_f32_16x16x16bf16_1k(fv, pb[sl], acc[h16], 0, 0, 0);
            }
        }
        __syncthreads();
        cur ^= 1;
    }
    float inv = 1.0f / lrun;
    #pragma unroll
    for (int h16 = 0; h16 < 4; h16++){
        f32x4 o = acc[h16] * inv;
        *(f32x4*)(out + (size_t)(b * 2048 + tw + lr) * 64 + h16 * 16 + lg * 4) = o;
    }
}

extern "C" void kernel_launch(void* const* d_in, const int* in_sizes, int n_in,
                              void* d_out, int out_size, void* d_ws, size_t ws_size,
                              hipStream_t stream) {
    const float* x  = (const float*)d_in[0];
    const float* Wk = (const float*)d_in[1];
    const float* Wq = (const float*)d_in[2];
    const float* Wv = (const float*)d_in[3];
    float* out = (float*)d_out;
    char* ws = (char*)d_ws;
    if (ws_size < (size_t)7 * 1024 * 1024) return;
    unsigned short* WT = (unsigned short*)(ws);              // 384 KB
    unsigned short* kb = (unsigned short*)(ws + (1u << 20)); // 2 MB (k * 0.125*log2e)
    unsigned short* qb = (unsigned short*)(ws + (3u << 20)); // 2 MB
    unsigned short* vT = (unsigned short*)(ws + (5u << 20)); // 2 MB ([b][h][t])
    hipLaunchKernelGGL(wprep_kernel, dim3(16, 3), dim3(256), 0, stream, Wk, Wq, Wv, WT);
    hipLaunchKernelGGL(proj_kernel, dim3(512), dim3(256), 0, stream, x, WT, kb, qb, vT);
    // attn partial buffers: accp = (NS-1) x 4MB at +7MB; ml after accp. NS=4 measured optimal
    // (NS=2: 50.2us, NS=4: 48.0us, NS=8: 53.6us).
    if (ws_size >= (size_t)20 * 1024 * 1024){
        float* accp = (float*)(ws + ((size_t)7 << 20));                      // 12 MB (3 arrays)
        float* ml   = (float*)(ws + ((size_t)19 << 20));                     // 512 KB
        hipLaunchKernelGGL((attn_part_kernel<4>), dim3(1024), dim3(256), 0, stream,
                           kb, qb, vT, out, accp, ml);
        hipLaunchKernelGGL((attn_merge_kernel<4>), dim3(256), dim3(256), 0, stream,
                           accp, ml, out);
    } else if (ws_size >= (size_t)12 * 1024 * 1024){
        float* accp = (float*)(ws + ((size_t)7 << 20));                      // 4 MB (1 array)
        float* ml   = (float*)(ws + ((size_t)11 << 20));                     // 256 KB
        hipLaunchKernelGGL((attn_part_kernel<2>), dim3(512), dim3(256), 0, stream,
                           kb, qb, vT, out, accp, ml);
        hipLaunchKernelGGL((attn_merge_kernel<2>), dim3(256), dim3(256), 0, stream,
                           accp, ml, out);
    } else {
        hipLaunchKernelGGL(attn_kernel, dim3(256), dim3(256), 0, stream, kb, qb, vT, out);
    }
}